// Round 15
// baseline (1102.286 us; speedup 1.0000x reference)
//
#include <hip/hip_runtime.h>
#include <hip/hip_bf16.h>
#include <float.h>

#define NN 50000
#define NE 800000
#define DF 96
#define DI 32
#define CO 128
#define NG 500
#define F1I 384
#define F1O 160
#define F2O 10
#define CAPLOG 7        // csr bucket capacity 128; max observed deg ~45
#define NRANGE 196      // dst>>8 ranges
#define EPB 3125        // edges per binA block (256 blocks)
#define RCAPLOG 13      // ebin region capacity 8192 (mean 4082)
#define NBLK 512        // 2 blocks/CU x 256 CUs — all co-resident
#define SMEM_BYTES 69632 // 256*(128+8)*2, max over phases; 2x fits in 160KB LDS/CU

typedef unsigned int  u32;
typedef unsigned short u16;
typedef short bf16x8 __attribute__((ext_vector_type(8)));
typedef float f32x4  __attribute__((ext_vector_type(4)));

__device__ __forceinline__ u16 f2b(float f) {
    __hip_bfloat16 h = __float2bfloat16(f);
    return *reinterpret_cast<u16*>(&h);
}
__device__ __forceinline__ float blo(u32 u) { return __uint_as_float(u << 16); }
__device__ __forceinline__ float bhi(u32 u) { return __uint_as_float(u & 0xffff0000u); }

struct P {
    const float* x; const int* batch; const float* info;
    const int* src; const int* dst;
    const float *Wl0, *Wr0, *b0, *Wl1, *Wr1, *b1, *Wl2, *Wr2, *b2;
    const float *Wfc1, *bfc1, *Wfc2, *bfc2;
    float* out;
    int* grescnt; int* bar; u32* ebin; int* start; u16* xb;
    u16 *WT0, *WT1, *WT2;
    float *iQl0, *iQr0, *iQl1, *iQr1, *iQl2, *iQr2;
    int* cnt; u16* csr;
    u16 *h1, *h2, *h3, *zlp, *zq;
};

// ---- software global barrier: one counter per phase, zeroed by pre-launch memset.
// Release atomicAdd + acquire spin (thread 0), s_sleep backoff, hang-proof cap.
__device__ void gbar(int* bar, int idx) {
    __syncthreads();
    if (threadIdx.x == 0) {
        __hip_atomic_fetch_add(&bar[idx * 16], 1, __ATOMIC_RELEASE, __HIP_MEMORY_SCOPE_AGENT);
        long long it = 0;
        while (__hip_atomic_load(&bar[idx * 16], __ATOMIC_ACQUIRE, __HIP_MEMORY_SCOPE_AGENT) < NBLK) {
            __builtin_amdgcn_s_sleep(8);
            if (++it > 20000000LL) break;   // escape instead of wedging the GPU
        }
    }
    __syncthreads();
}

// ---------------- phase pieces (R12-proven bodies) ----------------

__device__ void sec_binA(int vb, const int* __restrict__ src, const int* __restrict__ dst,
                         int* __restrict__ grescnt, u32* __restrict__ ebin, char* smem) {
    u32* pairs = (u32*)smem;
    int* lcnt  = (int*)(smem + EPB * 4);
    int t = threadIdx.x;
    int base = vb * EPB;
    lcnt[t] = 0;
    __syncthreads();
    for (int j = t; j < EPB; j += 256) {
        int e = base + j;
        int d = dst[e];
        int s = src[e];
        pairs[j] = ((u32)(d & 255) << 24) | ((u32)(d >> 8) << 16) | (u32)s;
        atomicAdd(&lcnt[d >> 8], 1);
    }
    __syncthreads();
    int myCnt = lcnt[t];
    int myBase = atomicAdd(&grescnt[t * 16], myCnt);
    __syncthreads();
    lcnt[t] = myBase;
    __syncthreads();
    for (int j = t; j < EPB; j += 256) {
        u32 pr = pairs[j];
        int r = (pr >> 16) & 255;
        int pos = atomicAdd(&lcnt[r], 1);
        if (pos < (1 << RCAPLOG)) ebin[(r << RCAPLOG) + pos] = pr;
    }
    __syncthreads();
}

__device__ void sec_starts(int vb, const int* __restrict__ batch, int* __restrict__ start) {
    int i = vb * 256 + threadIdx.x;
    if (i >= NN) return;
    int b = batch[i];
    if (i == 0) { for (int g = 0; g <= b; ++g) start[g] = 0; }
    else {
        int p = batch[i - 1];
        if (p != b) for (int g = p + 1; g <= b; ++g) start[g] = i;
    }
    if (i == NN - 1) { for (int g = b + 1; g <= NG; ++g) start[g] = NN; }
}

__device__ void sec_binB(int r, const u32* __restrict__ ebin, const int* __restrict__ grescnt,
                         int* __restrict__ cnt, u16* __restrict__ csr, char* smem) {
    int* lcnt = (int*)smem;
    int t = threadIdx.x;
    lcnt[t] = 0;
    __syncthreads();
    int total = grescnt[r * 16];
    if (total > (1 << RCAPLOG)) total = 1 << RCAPLOG;
    for (int j = t; j < total; j += 256) {
        u32 p = ebin[(r << RCAPLOG) + j];
        int dloc = p >> 24;
        int rank = atomicAdd(&lcnt[dloc], 1);
        int node = (r << 8) + dloc;
        if (rank < (1 << CAPLOG)) csr[(node << CAPLOG) + rank] = (u16)(p & 0xffff);
    }
    __syncthreads();
    int node = (r << 8) + t;
    if (node < NN) cnt[node] = lcnt[t];
    __syncthreads();
}

__device__ void sec_cast(int vb, const float* __restrict__ x, u16* __restrict__ xb) {
    int tid = vb * 256 + threadIdx.x;
    if (tid >= NN * DF / 4) return;
    float4 v = *(const float4*)&x[tid * 4];
    ushort4 o;
    o.x = f2b(v.x); o.y = f2b(v.y); o.z = f2b(v.z); o.w = f2b(v.w);
    *(ushort4*)&xb[tid * 4] = o;
}

__device__ void sec_wt(int rel, const float* __restrict__ Wl, const float* __restrict__ Wr,
                       u16* __restrict__ WT, int K) {
    int tid = rel * 256 + threadIdx.x;
    if (tid >= 256 * K) return;
    int n = tid / K;
    int k = tid - n * K;
    float v = (n < CO) ? Wl[k * CO + n] : Wr[k * CO + (n - CO)];
    WT[tid] = f2b(v);
}

__device__ void sec_infow(int g, const float* __restrict__ info,
                          const float* __restrict__ Wl, const float* __restrict__ Wr,
                          const float* __restrict__ bias, int Ktop,
                          float* __restrict__ iQl, float* __restrict__ iQr) {
    int t = threadIdx.x;
    int c = t & 127;
    int sel = t >> 7;
    const float* W = sel ? Wr : Wl;
    float a = sel ? bias[c] : 0.0f;
    for (int d = 0; d < DI; ++d)
        a += info[g * DI + d] * W[(Ktop + d) * CO + c];
    (sel ? iQr : iQl)[g * CO + c] = a;
}

// R12-proven full-LDS MFMA + fused combine
template<int K>
__device__ void sec_mfma(int vb, const u16* __restrict__ A, const u16* __restrict__ WTg,
                         const int* __restrict__ batch,
                         const float* __restrict__ iQl, const float* __restrict__ iQr,
                         u16* __restrict__ zlp, u16* __restrict__ zq, char* smem) {
    constexpr int PITCH = K + 8;
    short* lds = (short*)smem;

    int tid  = threadIdx.x;
    int w    = tid >> 6;
    int lane = tid & 63;
    int quad = lane >> 4;
    int l15  = lane & 15;

    constexpr int CH = 256 * K / 8;
    const uint4* wp = (const uint4*)WTg;
    for (int c = tid; c < CH; c += 256) {
        int n  = c / (K / 8);
        int ko = (c - n * (K / 8)) * 8;
        *(uint4*)&lds[n * PITCH + ko] = wp[c];
    }
    __syncthreads();

    int i0 = vb * 128 + w * 32;
    int r0 = i0 + l15;       if (r0 >= NN) r0 = NN - 1;
    int r1 = i0 + 16 + l15;  if (r1 >= NN) r1 = NN - 1;
    const short* A0 = (const short*)A + (size_t)r0 * K;
    const short* A1 = (const short*)A + (size_t)r1 * K;

    f32x4 acc[2][16];
#pragma unroll
    for (int rt = 0; rt < 2; ++rt)
#pragma unroll
        for (int ct = 0; ct < 16; ++ct)
            acc[rt][ct] = (f32x4){0.f, 0.f, 0.f, 0.f};

#pragma unroll
    for (int ks = 0; ks < K / 32; ++ks) {
        int ka = ks * 32 + quad * 8;
        bf16x8 a0 = *(const bf16x8*)(A0 + ka);
        bf16x8 a1 = *(const bf16x8*)(A1 + ka);
#pragma unroll
        for (int ct = 0; ct < 16; ++ct) {
            bf16x8 b = *(const bf16x8*)&lds[(ct * 16 + l15) * PITCH + ka];
            acc[0][ct] = __builtin_amdgcn_mfma_f32_16x16x32_bf16(a0, b, acc[0][ct], 0, 0, 0);
            acc[1][ct] = __builtin_amdgcn_mfma_f32_16x16x32_bf16(a1, b, acc[1][ct], 0, 0, 0);
        }
    }

#pragma unroll
    for (int rt = 0; rt < 2; ++rt) {
#pragma unroll
        for (int reg = 0; reg < 4; ++reg) {
            int row = i0 + rt * 16 + quad * 4 + reg;
            if (row < NN) {
                int b = batch[row];
                const float* ql = &iQl[b * CO];
                const float* qr = &iQr[b * CO];
                u16* lp = zlp + (size_t)row * CO;
                u16* qp = zq  + (size_t)row * CO;
#pragma unroll
                for (int ct = 0; ct < 8; ++ct) {
                    int col = ct * 16 + l15;
                    lp[col] = f2b(acc[rt][ct][reg] + ql[col]);
                }
#pragma unroll
                for (int ct = 8; ct < 16; ++ct) {
                    int col = ct * 16 + l15 - 128;
                    qp[col] = f2b(acc[rt][ct][reg] + qr[col]);
                }
            }
        }
    }
    __syncthreads();
}

__device__ __forceinline__ void acc8(float* a, const uint4& u) {
    a[0] += blo(u.x); a[1] += bhi(u.x);
    a[2] += blo(u.y); a[3] += bhi(u.y);
    a[4] += blo(u.z); a[5] += bhi(u.z);
    a[6] += blo(u.w); a[7] += bhi(u.w);
}

__device__ void sec_gather(int vb, const u32* __restrict__ zlp, const u32* __restrict__ zq,
                           const int* __restrict__ cnt, const u16* __restrict__ csr,
                           u32* __restrict__ hout) {
    int wave = threadIdx.x >> 6;
    int lane = threadIdx.x & 63;
    int q    = lane >> 4;
    int l16  = lane & 15;
    int i = vb * 4 + wave;
    if (i >= NN) return;
    int deg = cnt[i];
    int degc = min(deg, 1 << CAPLOG);
    int s0 = i << CAPLOG;
    int s1 = s0 + degc;

    const uint4* Z = (const uint4*)zlp;

    float a[8] = {0,0,0,0,0,0,0,0};
    float b[8] = {0,0,0,0,0,0,0,0};
    float c[8] = {0,0,0,0,0,0,0,0};
    float d[8] = {0,0,0,0,0,0,0,0};

    int e = s0;
    for (; e + 15 < s1; e += 16) {
        int n0 = csr[e + q];
        int n1 = csr[e + 4 + q];
        int n2 = csr[e + 8 + q];
        int n3 = csr[e + 12 + q];
        uint4 u0 = Z[(size_t)n0 * 16 + l16];
        uint4 u1 = Z[(size_t)n1 * 16 + l16];
        uint4 u2 = Z[(size_t)n2 * 16 + l16];
        uint4 u3 = Z[(size_t)n3 * 16 + l16];
        acc8(a, u0); acc8(b, u1); acc8(c, u2); acc8(d, u3);
    }
    for (; e < s1; e += 4) {
        if (e + q < s1) {
            int n0 = csr[e + q];
            uint4 u0 = Z[(size_t)n0 * 16 + l16];
            acc8(a, u0);
        }
    }
#pragma unroll
    for (int j = 0; j < 8; ++j) {
        a[j] += b[j] + c[j] + d[j];
        a[j] += __shfl_xor(a[j], 16);
        a[j] += __shfl_xor(a[j], 32);
    }
    if (q == 0) {
        float r = 1.0f / fmaxf((float)deg, 1.0f);
        uint4 qq = ((const uint4*)zq)[(size_t)i * 16 + l16];
        uint4 o;
        o.x = (u32)f2b(a[0] * r + blo(qq.x)) | ((u32)f2b(a[1] * r + bhi(qq.x)) << 16);
        o.y = (u32)f2b(a[2] * r + blo(qq.y)) | ((u32)f2b(a[3] * r + bhi(qq.y)) << 16);
        o.z = (u32)f2b(a[4] * r + blo(qq.z)) | ((u32)f2b(a[5] * r + bhi(qq.z)) << 16);
        o.w = (u32)f2b(a[6] * r + blo(qq.w)) | ((u32)f2b(a[7] * r + bhi(qq.w)) << 16);
        ((uint4*)hout)[(size_t)i * 16 + l16] = o;
    }
}

__device__ void sec_poolfc(int gr, const u32* __restrict__ h1, const u32* __restrict__ h2,
                           const u32* __restrict__ h3, const int* __restrict__ start,
                           const float* __restrict__ W1, const float* __restrict__ b1,
                           const float* __restrict__ W2, const float* __restrict__ b2,
                           float* __restrict__ out, char* smem) {
    float* s_g = (float*)smem;
    float* s_z = (float*)smem + F1I;
    int t = threadIdx.x;
    int w = t >> 6, lane = t & 63;
    if (w < 3) {
        const u32* hb = (w == 0) ? h1 : (w == 1) ? h2 : h3;
        int s = start[gr], e = start[gr + 1];
        float mlo[4], mhi[4];
#pragma unroll
        for (int j = 0; j < 4; ++j) { mlo[j] = -FLT_MAX; mhi[j] = -FLT_MAX; }
        int n = s;
        for (; n + 3 < e; n += 4) {
            u32 v0 = hb[(size_t)(n + 0) * 64 + lane];
            u32 v1 = hb[(size_t)(n + 1) * 64 + lane];
            u32 v2 = hb[(size_t)(n + 2) * 64 + lane];
            u32 v3 = hb[(size_t)(n + 3) * 64 + lane];
            mlo[0] = fmaxf(mlo[0], blo(v0)); mhi[0] = fmaxf(mhi[0], bhi(v0));
            mlo[1] = fmaxf(mlo[1], blo(v1)); mhi[1] = fmaxf(mhi[1], bhi(v1));
            mlo[2] = fmaxf(mlo[2], blo(v2)); mhi[2] = fmaxf(mhi[2], bhi(v2));
            mlo[3] = fmaxf(mlo[3], blo(v3)); mhi[3] = fmaxf(mhi[3], bhi(v3));
        }
        for (; n < e; ++n) {
            u32 v0 = hb[(size_t)n * 64 + lane];
            mlo[0] = fmaxf(mlo[0], blo(v0)); mhi[0] = fmaxf(mhi[0], bhi(v0));
        }
        float lo = fmaxf(fmaxf(mlo[0], mlo[1]), fmaxf(mlo[2], mlo[3]));
        float hi = fmaxf(fmaxf(mhi[0], mhi[1]), fmaxf(mhi[2], mhi[3]));
        s_g[w * 128 + 2 * lane]     = lo;
        s_g[w * 128 + 2 * lane + 1] = hi;
    }
    __syncthreads();
    if (t < F1O) {
        float acc = b1[t];
        for (int k = 0; k < F1I; ++k) acc += s_g[k] * W1[k * F1O + t];
        s_z[t] = fmaxf(acc, 0.0f);
    }
    __syncthreads();
    if (t < F2O) {
        float a = b2[t];
        for (int k = 0; k < F1O; ++k) a += s_z[k] * W2[k * F2O + t];
        out[gr * F2O + t] = a;
    }
    __syncthreads();
}

// ---------------- mega kernel (normal launch, software barriers) ----------------
#define P2_BINB   NRANGE
#define P2_CAST   4688
#define P2_WT     352
#define P2_INFO   1500
#define P2_TOTAL  (P2_BINB + P2_CAST + P2_WT + P2_INFO)

__global__ __launch_bounds__(256, 2) void k_mega(P p) {
    __shared__ __align__(16) char smem[SMEM_BYTES];
    int blk = blockIdx.x;

    // P1: binA | starts   (grescnt + bar zeroed by pre-launch memset)
    if (blk < 256) {
        sec_binA(blk, p.src, p.dst, p.grescnt, p.ebin, smem);
    } else if (blk < 256 + 196) {
        sec_starts(blk - 256, p.batch, p.start);
    }
    gbar(p.bar, 0);

    // P2: binB | cast | wt | infow
    for (int vb = blk; vb < P2_TOTAL; vb += NBLK) {
        if (vb < P2_BINB) {
            sec_binB(vb, p.ebin, p.grescnt, p.cnt, p.csr, smem);
        } else if (vb < P2_BINB + P2_CAST) {
            sec_cast(vb - P2_BINB, p.x, p.xb);
        } else if (vb < P2_BINB + P2_CAST + P2_WT) {
            int r = vb - P2_BINB - P2_CAST;
            if (r < 96)       sec_wt(r, p.Wl0, p.Wr0, p.WT0, 96);
            else if (r < 224) sec_wt(r - 96, p.Wl1, p.Wr1, p.WT1, 128);
            else              sec_wt(r - 224, p.Wl2, p.Wr2, p.WT2, 128);
        } else {
            int g = vb - P2_BINB - P2_CAST - P2_WT;
            if (g < 500)       sec_infow(g, p.info, p.Wl0, p.Wr0, p.b0, 96,  p.iQl0, p.iQr0);
            else if (g < 1000) sec_infow(g - 500, p.info, p.Wl1, p.Wr1, p.b1, 128, p.iQl1, p.iQr1);
            else               sec_infow(g - 1000, p.info, p.Wl2, p.Wr2, p.b2, 128, p.iQl2, p.iQr2);
        }
    }
    gbar(p.bar, 1);

    const int gGemm = (NN + 127) / 128;    // 391
    const int gGath = (NN + 3) / 4;        // 12500

    // layer 0
    if (blk < gGemm)
        sec_mfma<96>(blk, p.xb, p.WT0, p.batch, p.iQl0, p.iQr0, p.zlp, p.zq, smem);
    gbar(p.bar, 2);
    for (int vb = blk; vb < gGath; vb += NBLK)
        sec_gather(vb, (const u32*)p.zlp, (const u32*)p.zq, p.cnt, p.csr, (u32*)p.h1);
    gbar(p.bar, 3);

    // layer 1
    if (blk < gGemm)
        sec_mfma<128>(blk, p.h1, p.WT1, p.batch, p.iQl1, p.iQr1, p.zlp, p.zq, smem);
    gbar(p.bar, 4);
    for (int vb = blk; vb < gGath; vb += NBLK)
        sec_gather(vb, (const u32*)p.zlp, (const u32*)p.zq, p.cnt, p.csr, (u32*)p.h2);
    gbar(p.bar, 5);

    // layer 2
    if (blk < gGemm)
        sec_mfma<128>(blk, p.h2, p.WT2, p.batch, p.iQl2, p.iQr2, p.zlp, p.zq, smem);
    gbar(p.bar, 6);
    for (int vb = blk; vb < gGath; vb += NBLK)
        sec_gather(vb, (const u32*)p.zlp, (const u32*)p.zq, p.cnt, p.csr, (u32*)p.h3);
    gbar(p.bar, 7);

    // poolfc
    if (blk < NG)
        sec_poolfc(blk, (const u32*)p.h1, (const u32*)p.h2, (const u32*)p.h3, p.start,
                   p.Wfc1, p.bfc1, p.Wfc2, p.bfc2, p.out, smem);
}

extern "C" void kernel_launch(void* const* d_in, const int* in_sizes, int n_in,
                              void* d_out, int out_size, void* d_ws, size_t ws_size,
                              hipStream_t stream) {
    const int* eidx = (const int*)d_in[1];

    char* W = (char*)d_ws;
    P p;
    p.x     = (const float*)d_in[0];
    p.batch = (const int*)d_in[2];
    p.info  = (const float*)d_in[3];
    p.src   = eidx;
    p.dst   = eidx + NE;
    p.Wl0 = (const float*)d_in[4];  p.Wr0 = (const float*)d_in[5];  p.b0 = (const float*)d_in[6];
    p.Wl1 = (const float*)d_in[7];  p.Wr1 = (const float*)d_in[8];  p.b1 = (const float*)d_in[9];
    p.Wl2 = (const float*)d_in[10]; p.Wr2 = (const float*)d_in[11]; p.b2 = (const float*)d_in[12];
    p.Wfc1 = (const float*)d_in[13]; p.bfc1 = (const float*)d_in[14];
    p.Wfc2 = (const float*)d_in[15]; p.bfc2 = (const float*)d_in[16];
    p.out = (float*)d_out;

    p.xb     = (u16*)(W + 0);             // 50000*96 bf16
    p.h1     = (u16*)(W + 9600000);       // 50000*128 bf16 each
    p.h2     = (u16*)(W + 22400000);
    p.h3     = (u16*)(W + 35200000);
    p.zlp    = (u16*)(W + 48000000);
    p.zq     = (u16*)(W + 60800000);
    p.WT0    = (u16*)(W + 73600000);
    p.WT1    = (u16*)(W + 73649152);
    p.WT2    = (u16*)(W + 73714688);
    p.iQl0   = (float*)(W + 73780224);
    p.iQr0   = (float*)(W + 74036224);
    p.iQl1   = (float*)(W + 74292224);
    p.iQr1   = (float*)(W + 74548224);
    p.iQl2   = (float*)(W + 74804224);
    p.iQr2   = (float*)(W + 75060224);
    p.start  = (int*)(W + 75316224);      // NG+1
    p.cnt    = (int*)(W + 75318272);      // NN
    p.csr    = (u16*)(W + 75518336);      // NN*128 u16 = 12.8 MB
    p.ebin   = (u32*)(W + 88318336);      // 256*8192 u32 = 8 MB
    p.grescnt= (int*)(W + 96706560);      // 256 x16 padded ints (16 KB)
    p.bar    = (int*)(W + 96722944);      // 16 x16 padded ints (1 KB)

    // one memset covers grescnt + barrier counters (contiguous)
    hipMemsetAsync(p.grescnt, 0, 256 * 16 * sizeof(int) + 16 * 16 * sizeof(int), stream);
    k_mega<<<NBLK, 256, 0, stream>>>(p);
}

// Round 16
// 357.224 us; speedup vs baseline: 3.0857x; 3.0857x over previous
//
#include <hip/hip_runtime.h>
#include <hip/hip_bf16.h>
#include <float.h>

#define NN 50000
#define NE 800000
#define DF 96
#define DI 32
#define CO 128
#define NG 500
#define F1I 384
#define F1O 160
#define F2O 10
#define CAPLOG 7        // csr bucket capacity 128; max observed deg ~45
#define NRANGE 196      // dst>>8 ranges
#define EPB 3125        // edges per binA block (256 blocks)
#define RCAPLOG 13      // ebin region capacity 8192 (mean 4082)
#define GGEMM 391       // ceil(NN/128)

typedef unsigned int  u32;
typedef unsigned short u16;
typedef short bf16x8 __attribute__((ext_vector_type(8)));
typedef float f32x4  __attribute__((ext_vector_type(4)));

__device__ __forceinline__ u16 f2b(float f) {
    __hip_bfloat16 h = __float2bfloat16(f);
    return *reinterpret_cast<u16*>(&h);
}
__device__ __forceinline__ float blo(u32 u) { return __uint_as_float(u << 16); }
__device__ __forceinline__ float bhi(u32 u) { return __uint_as_float(u & 0xffff0000u); }

struct P {
    const float* x; const int* batch; const float* info;
    const int* src; const int* dst;
    const float *Wl0, *Wr0, *b0, *Wl1, *Wr1, *b1, *Wl2, *Wr2, *b2;
    const float *Wfc1, *bfc1, *Wfc2, *bfc2;
    float* out;
    int* grescnt; u32* ebin; int* start; u16* xb;
    u16 *WT0, *WT1, *WT2;
    float *iQl0, *iQr0, *iQl1, *iQr1, *iQl2, *iQr2;
    int* cnt; u16* csr;
    u16 *h1, *h2, *h3, *zlp, *zq;
    float* gpart;
};

// ---------------- phase pieces (R12-proven bodies) ----------------

__device__ void sec_binA(int vb, const int* __restrict__ src, const int* __restrict__ dst,
                         int* __restrict__ grescnt, u32* __restrict__ ebin, char* smem) {
    u32* pairs = (u32*)smem;
    int* lcnt  = (int*)(smem + EPB * 4);
    int t = threadIdx.x;
    int base = vb * EPB;
    lcnt[t] = 0;
    __syncthreads();
    for (int j = t; j < EPB; j += 256) {
        int e = base + j;
        int d = dst[e];
        int s = src[e];
        pairs[j] = ((u32)(d & 255) << 24) | ((u32)(d >> 8) << 16) | (u32)s;
        atomicAdd(&lcnt[d >> 8], 1);
    }
    __syncthreads();
    int myCnt = lcnt[t];
    int myBase = atomicAdd(&grescnt[t * 16], myCnt);   // padded: 1 counter per 64B line
    __syncthreads();
    lcnt[t] = myBase;
    __syncthreads();
    for (int j = t; j < EPB; j += 256) {
        u32 pr = pairs[j];
        int r = (pr >> 16) & 255;
        int pos = atomicAdd(&lcnt[r], 1);
        if (pos < (1 << RCAPLOG)) ebin[(r << RCAPLOG) + pos] = pr;
    }
}

__device__ void sec_starts(int vb, const int* __restrict__ batch, int* __restrict__ start) {
    int i = vb * 256 + threadIdx.x;
    if (i >= NN) return;
    int b = batch[i];
    if (i == 0) { for (int g = 0; g <= b; ++g) start[g] = 0; }
    else {
        int p = batch[i - 1];
        if (p != b) for (int g = p + 1; g <= b; ++g) start[g] = i;
    }
    if (i == NN - 1) { for (int g = b + 1; g <= NG; ++g) start[g] = NN; }
}

__device__ void sec_binB(int r, const u32* __restrict__ ebin, const int* __restrict__ grescnt,
                         int* __restrict__ cnt, u16* __restrict__ csr, char* smem) {
    int* lcnt = (int*)smem;
    int t = threadIdx.x;
    lcnt[t] = 0;
    __syncthreads();
    int total = grescnt[r * 16];
    if (total > (1 << RCAPLOG)) total = 1 << RCAPLOG;
    for (int j = t; j < total; j += 256) {
        u32 p = ebin[(r << RCAPLOG) + j];
        int dloc = p >> 24;
        int rank = atomicAdd(&lcnt[dloc], 1);
        int node = (r << 8) + dloc;
        if (rank < (1 << CAPLOG)) csr[(node << CAPLOG) + rank] = (u16)(p & 0xffff);
    }
    __syncthreads();
    int node = (r << 8) + t;
    if (node < NN) cnt[node] = lcnt[t];
}

__device__ void sec_cast(int vb, const float* __restrict__ x, u16* __restrict__ xb) {
    int tid = vb * 256 + threadIdx.x;
    if (tid >= NN * DF / 4) return;
    float4 v = *(const float4*)&x[tid * 4];
    ushort4 o;
    o.x = f2b(v.x); o.y = f2b(v.y); o.z = f2b(v.z); o.w = f2b(v.w);
    *(ushort4*)&xb[tid * 4] = o;
}

__device__ void sec_wt(int rel, const float* __restrict__ Wl, const float* __restrict__ Wr,
                       u16* __restrict__ WT, int K) {
    int tid = rel * 256 + threadIdx.x;
    if (tid >= 256 * K) return;
    int n = tid / K;
    int k = tid - n * K;
    float v = (n < CO) ? Wl[k * CO + n] : Wr[k * CO + (n - CO)];
    WT[tid] = f2b(v);
}

__device__ void sec_infow(int g, const float* __restrict__ info,
                          const float* __restrict__ Wl, const float* __restrict__ Wr,
                          const float* __restrict__ bias, int Ktop,
                          float* __restrict__ iQl, float* __restrict__ iQr) {
    int t = threadIdx.x;
    int c = t & 127;
    int sel = t >> 7;
    const float* W = sel ? Wr : Wl;
    float a = sel ? bias[c] : 0.0f;
    for (int d = 0; d < DI; ++d)
        a += info[g * DI + d] * W[(Ktop + d) * CO + c];
    (sel ? iQr : iQl)[g * CO + c] = a;
}

template<int K>
__device__ void sec_mfma(int vb, const u16* __restrict__ A, const u16* __restrict__ WTg,
                         const int* __restrict__ batch,
                         const float* __restrict__ iQl, const float* __restrict__ iQr,
                         u16* __restrict__ zlp, u16* __restrict__ zq, char* smem) {
    constexpr int PITCH = K + 8;
    short* lds = (short*)smem;

    int tid  = threadIdx.x;
    int w    = tid >> 6;
    int lane = tid & 63;
    int quad = lane >> 4;
    int l15  = lane & 15;

    constexpr int CH = 256 * K / 8;
    const uint4* wp = (const uint4*)WTg;
    for (int c = tid; c < CH; c += 256) {
        int n  = c / (K / 8);
        int ko = (c - n * (K / 8)) * 8;
        *(uint4*)&lds[n * PITCH + ko] = wp[c];
    }
    __syncthreads();

    int i0 = vb * 128 + w * 32;
    int r0 = i0 + l15;       if (r0 >= NN) r0 = NN - 1;
    int r1 = i0 + 16 + l15;  if (r1 >= NN) r1 = NN - 1;
    const short* A0 = (const short*)A + (size_t)r0 * K;
    const short* A1 = (const short*)A + (size_t)r1 * K;

    f32x4 acc[2][16];
#pragma unroll
    for (int rt = 0; rt < 2; ++rt)
#pragma unroll
        for (int ct = 0; ct < 16; ++ct)
            acc[rt][ct] = (f32x4){0.f, 0.f, 0.f, 0.f};

#pragma unroll
    for (int ks = 0; ks < K / 32; ++ks) {
        int ka = ks * 32 + quad * 8;
        bf16x8 a0 = *(const bf16x8*)(A0 + ka);
        bf16x8 a1 = *(const bf16x8*)(A1 + ka);
#pragma unroll
        for (int ct = 0; ct < 16; ++ct) {
            bf16x8 b = *(const bf16x8*)&lds[(ct * 16 + l15) * PITCH + ka];
            acc[0][ct] = __builtin_amdgcn_mfma_f32_16x16x32_bf16(a0, b, acc[0][ct], 0, 0, 0);
            acc[1][ct] = __builtin_amdgcn_mfma_f32_16x16x32_bf16(a1, b, acc[1][ct], 0, 0, 0);
        }
    }

#pragma unroll
    for (int rt = 0; rt < 2; ++rt) {
#pragma unroll
        for (int reg = 0; reg < 4; ++reg) {
            int row = i0 + rt * 16 + quad * 4 + reg;
            if (row < NN) {
                int b = batch[row];
                const float* ql = &iQl[b * CO];
                const float* qr = &iQr[b * CO];
                u16* lp = zlp + (size_t)row * CO;
                u16* qp = zq  + (size_t)row * CO;
#pragma unroll
                for (int ct = 0; ct < 8; ++ct) {
                    int col = ct * 16 + l15;
                    lp[col] = f2b(acc[rt][ct][reg] + ql[col]);
                }
#pragma unroll
                for (int ct = 8; ct < 16; ++ct) {
                    int col = ct * 16 + l15 - 128;
                    qp[col] = f2b(acc[rt][ct][reg] + qr[col]);
                }
            }
        }
    }
}

// partial pool of one h-buffer (256 threads, 4 waves split the node range)
__device__ void sec_poolpart(int gr, const u32* __restrict__ hb, const int* __restrict__ start,
                             float* __restrict__ gpart, int off) {
    __shared__ float s_part[4][128];
    int t = threadIdx.x, w = t >> 6, lane = t & 63;
    int s = start[gr], e = start[gr + 1];
    float mlo = -FLT_MAX, mhi = -FLT_MAX;
    for (int n = s + w; n < e; n += 4) {
        u32 v = hb[(size_t)n * 64 + lane];
        mlo = fmaxf(mlo, blo(v)); mhi = fmaxf(mhi, bhi(v));
    }
    s_part[w][2 * lane]     = mlo;
    s_part[w][2 * lane + 1] = mhi;
    __syncthreads();
    if (t < 128) {
        float m = fmaxf(fmaxf(s_part[0][t], s_part[1][t]), fmaxf(s_part[2][t], s_part[3][t]));
        gpart[gr * 256 + off + t] = m;
    }
}

__device__ __forceinline__ void acc8(float* a, const uint4& u) {
    a[0] += blo(u.x); a[1] += bhi(u.x);
    a[2] += blo(u.y); a[3] += bhi(u.y);
    a[4] += blo(u.z); a[5] += bhi(u.z);
    a[6] += blo(u.w); a[7] += bhi(u.w);
}

__device__ void sec_gather(int vb, const u32* __restrict__ zlp, const u32* __restrict__ zq,
                           const int* __restrict__ cnt, const u16* __restrict__ csr,
                           u32* __restrict__ hout) {
    int wave = threadIdx.x >> 6;
    int lane = threadIdx.x & 63;
    int q    = lane >> 4;
    int l16  = lane & 15;
    int i = vb * 4 + wave;
    if (i >= NN) return;
    int deg = cnt[i];
    int degc = min(deg, 1 << CAPLOG);
    int s0 = i << CAPLOG;
    int s1 = s0 + degc;

    const uint4* Z = (const uint4*)zlp;

    float a[8] = {0,0,0,0,0,0,0,0};
    float b[8] = {0,0,0,0,0,0,0,0};
    float c[8] = {0,0,0,0,0,0,0,0};
    float d[8] = {0,0,0,0,0,0,0,0};

    int e = s0;
    for (; e + 15 < s1; e += 16) {
        int n0 = csr[e + q];
        int n1 = csr[e + 4 + q];
        int n2 = csr[e + 8 + q];
        int n3 = csr[e + 12 + q];
        uint4 u0 = Z[(size_t)n0 * 16 + l16];
        uint4 u1 = Z[(size_t)n1 * 16 + l16];
        uint4 u2 = Z[(size_t)n2 * 16 + l16];
        uint4 u3 = Z[(size_t)n3 * 16 + l16];
        acc8(a, u0); acc8(b, u1); acc8(c, u2); acc8(d, u3);
    }
    for (; e < s1; e += 4) {
        if (e + q < s1) {
            int n0 = csr[e + q];
            uint4 u0 = Z[(size_t)n0 * 16 + l16];
            acc8(a, u0);
        }
    }
#pragma unroll
    for (int j = 0; j < 8; ++j) {
        a[j] += b[j] + c[j] + d[j];
        a[j] += __shfl_xor(a[j], 16);
        a[j] += __shfl_xor(a[j], 32);
    }
    if (q == 0) {
        float r = 1.0f / fmaxf((float)deg, 1.0f);
        uint4 qq = ((const uint4*)zq)[(size_t)i * 16 + l16];
        uint4 o;
        o.x = (u32)f2b(a[0] * r + blo(qq.x)) | ((u32)f2b(a[1] * r + bhi(qq.x)) << 16);
        o.y = (u32)f2b(a[2] * r + blo(qq.y)) | ((u32)f2b(a[3] * r + bhi(qq.y)) << 16);
        o.z = (u32)f2b(a[4] * r + blo(qq.z)) | ((u32)f2b(a[5] * r + bhi(qq.z)) << 16);
        o.w = (u32)f2b(a[6] * r + blo(qq.w)) | ((u32)f2b(a[7] * r + bhi(qq.w)) << 16);
        ((uint4*)hout)[(size_t)i * 16 + l16] = o;
    }
}

// ---------------- kernels ----------------

// prep: binA | starts | cast | wt x3 | infow x3  (same layout as R12)
#define PB_BIN    256
#define PB_STARTS 196
#define PB_CAST   4688
#define PB_WT     352
#define PB_INFO   1500
#define PREP_GRID (PB_BIN + PB_STARTS + PB_CAST + PB_WT + PB_INFO)

__global__ __launch_bounds__(256) void k_prep(P p) {
    __shared__ __align__(16) char smem[EPB * 4 + 1024];
    int blk = blockIdx.x;
    if (blk < PB_BIN) { sec_binA(blk, p.src, p.dst, p.grescnt, p.ebin, smem); return; }
    blk -= PB_BIN;
    if (blk < PB_STARTS) { sec_starts(blk, p.batch, p.start); return; }
    blk -= PB_STARTS;
    if (blk < PB_CAST) { sec_cast(blk, p.x, p.xb); return; }
    blk -= PB_CAST;
    if (blk < PB_WT) {
        if (blk < 96)       sec_wt(blk, p.Wl0, p.Wr0, p.WT0, 96);
        else if (blk < 224) sec_wt(blk - 96, p.Wl1, p.Wr1, p.WT1, 128);
        else                sec_wt(blk - 224, p.Wl2, p.Wr2, p.WT2, 128);
        return;
    }
    blk -= PB_WT;
    if (blk < 500)       sec_infow(blk, p.info, p.Wl0, p.Wr0, p.b0, 96,  p.iQl0, p.iQr0);
    else if (blk < 1000) sec_infow(blk - 500, p.info, p.Wl1, p.Wr1, p.b1, 128, p.iQl1, p.iQr1);
    else                 sec_infow(blk - 1000, p.info, p.Wl2, p.Wr2, p.b2, 128, p.iQl2, p.iQr2);
}

// l0: binB (196) || mfma<96> (391) — independent, packed in one dispatch
__global__ __launch_bounds__(256) void k_l0(P p) {
    __shared__ __align__(16) char smem[256 * (96 + 8) * 2];
    int blk = blockIdx.x;
    if (blk < NRANGE) sec_binB(blk, p.ebin, p.grescnt, p.cnt, p.csr, smem);
    else              sec_mfma<96>(blk - NRANGE, p.xb, p.WT0, p.batch, p.iQl0, p.iQr0,
                                   p.zlp, p.zq, smem);
}

// l1: mfma<128> on h1 (391) || pool-h1 (500)
__global__ __launch_bounds__(256) void k_l1(P p) {
    __shared__ __align__(16) char smem[256 * (128 + 8) * 2];
    int blk = blockIdx.x;
    if (blk < GGEMM) sec_mfma<128>(blk, p.h1, p.WT1, p.batch, p.iQl1, p.iQr1, p.zlp, p.zq, smem);
    else             sec_poolpart(blk - GGEMM, (const u32*)p.h1, p.start, p.gpart, 0);
}

// l2: mfma<128> on h2 (391) || pool-h2 (500)
__global__ __launch_bounds__(256) void k_l2(P p) {
    __shared__ __align__(16) char smem[256 * (128 + 8) * 2];
    int blk = blockIdx.x;
    if (blk < GGEMM) sec_mfma<128>(blk, p.h2, p.WT2, p.batch, p.iQl2, p.iQr2, p.zlp, p.zq, smem);
    else             sec_poolpart(blk - GGEMM, (const u32*)p.h2, p.start, p.gpart, 128);
}

__global__ __launch_bounds__(256) void k_g(P p, const u16* hout) {
    sec_gather(blockIdx.x, (const u32*)p.zlp, (const u32*)p.zq, p.cnt, p.csr, (u32*)hout);
}

// final: pool h3 + FC head (gpart supplies h1/h2 maxes)
__global__ __launch_bounds__(256) void k_pf(P p) {
    __shared__ float s_g[F1I];
    __shared__ float s_z[F1O];
    __shared__ float s_part[4][128];
    int gr = blockIdx.x;
    int t = threadIdx.x, w = t >> 6, lane = t & 63;
    int s = p.start[gr], e = p.start[gr + 1];
    const u32* hb = (const u32*)p.h3;
    float mlo = -FLT_MAX, mhi = -FLT_MAX;
    for (int n = s + w; n < e; n += 4) {
        u32 v = hb[(size_t)n * 64 + lane];
        mlo = fmaxf(mlo, blo(v)); mhi = fmaxf(mhi, bhi(v));
    }
    s_part[w][2 * lane]     = mlo;
    s_part[w][2 * lane + 1] = mhi;
    s_g[t] = p.gpart[gr * 256 + t];            // cols 0..255 from h1/h2 partial pools
    __syncthreads();
    if (t < 128)
        s_g[256 + t] = fmaxf(fmaxf(s_part[0][t], s_part[1][t]),
                             fmaxf(s_part[2][t], s_part[3][t]));
    __syncthreads();
    if (t < F1O) {
        float acc = p.bfc1[t];
        for (int k = 0; k < F1I; ++k) acc += s_g[k] * p.Wfc1[k * F1O + t];
        s_z[t] = fmaxf(acc, 0.0f);
    }
    __syncthreads();
    if (t < F2O) {
        float a = p.bfc2[t];
        for (int k = 0; k < F1O; ++k) a += s_z[k] * p.Wfc2[k * F2O + t];
        p.out[gr * F2O + t] = a;
    }
}

extern "C" void kernel_launch(void* const* d_in, const int* in_sizes, int n_in,
                              void* d_out, int out_size, void* d_ws, size_t ws_size,
                              hipStream_t stream) {
    const int* eidx = (const int*)d_in[1];

    char* W = (char*)d_ws;
    P p;
    p.x     = (const float*)d_in[0];
    p.batch = (const int*)d_in[2];
    p.info  = (const float*)d_in[3];
    p.src   = eidx;
    p.dst   = eidx + NE;
    p.Wl0 = (const float*)d_in[4];  p.Wr0 = (const float*)d_in[5];  p.b0 = (const float*)d_in[6];
    p.Wl1 = (const float*)d_in[7];  p.Wr1 = (const float*)d_in[8];  p.b1 = (const float*)d_in[9];
    p.Wl2 = (const float*)d_in[10]; p.Wr2 = (const float*)d_in[11]; p.b2 = (const float*)d_in[12];
    p.Wfc1 = (const float*)d_in[13]; p.bfc1 = (const float*)d_in[14];
    p.Wfc2 = (const float*)d_in[15]; p.bfc2 = (const float*)d_in[16];
    p.out = (float*)d_out;

    p.xb     = (u16*)(W + 0);             // 50000*96 bf16
    p.h1     = (u16*)(W + 9600000);       // 50000*128 bf16 each
    p.h2     = (u16*)(W + 22400000);
    p.h3     = (u16*)(W + 35200000);
    p.zlp    = (u16*)(W + 48000000);
    p.zq     = (u16*)(W + 60800000);
    p.WT0    = (u16*)(W + 73600000);
    p.WT1    = (u16*)(W + 73649152);
    p.WT2    = (u16*)(W + 73714688);
    p.iQl0   = (float*)(W + 73780224);
    p.iQr0   = (float*)(W + 74036224);
    p.iQl1   = (float*)(W + 74292224);
    p.iQr1   = (float*)(W + 74548224);
    p.iQl2   = (float*)(W + 74804224);
    p.iQr2   = (float*)(W + 75060224);
    p.start  = (int*)(W + 75316224);      // NG+1
    p.cnt    = (int*)(W + 75318272);      // NN
    p.csr    = (u16*)(W + 75518336);      // NN*128 u16 = 12.8 MB
    p.ebin   = (u32*)(W + 88318336);      // ranges 0..195 used (<= 6.5 MB)
    p.grescnt= (int*)(W + 96706560);      // 256 x16 padded ints (16 KB)
    p.gpart  = (float*)(W + 96722944);    // 500 x 256 f32 (512 KB)

    hipMemsetAsync(p.grescnt, 0, 256 * 16 * sizeof(int), stream);
    k_prep<<<PREP_GRID, 256, 0, stream>>>(p);
    k_l0<<<NRANGE + GGEMM, 256, 0, stream>>>(p);
    k_g<<<(NN + 3) / 4, 256, 0, stream>>>(p, p.h1);
    k_l1<<<GGEMM + NG, 256, 0, stream>>>(p);
    k_g<<<(NN + 3) / 4, 256, 0, stream>>>(p, p.h2);
    k_l2<<<GGEMM + NG, 256, 0, stream>>>(p);
    k_g<<<(NN + 3) / 4, 256, 0, stream>>>(p, p.h3);
    k_pf<<<NG, 256, 0, stream>>>(p);
}

// Round 17
// 313.252 us; speedup vs baseline: 3.5189x; 1.1404x over previous
//
#include <hip/hip_runtime.h>
#include <hip/hip_bf16.h>
#include <float.h>

#define NN 50000
#define NE 800000
#define DF 96
#define DI 32
#define CO 128
#define NG 500
#define F1I 384
#define F1O 160
#define F2O 10
#define CAPLOG 7        // csr bucket capacity 128; max observed deg ~45
#define NRANGE 196      // dst>>8 ranges
#define EPB 3125        // edges per binA block (256 blocks)
#define RCAPLOG 13      // ebin region capacity 8192 (mean 4082)
#define GGEMM 391       // ceil(NN/128)
#define GGATH 12500     // ceil(NN/4)

typedef unsigned int  u32;
typedef unsigned short u16;
typedef short bf16x8 __attribute__((ext_vector_type(8)));
typedef float f32x4  __attribute__((ext_vector_type(4)));

__device__ __forceinline__ u16 f2b(float f) {
    __hip_bfloat16 h = __float2bfloat16(f);
    return *reinterpret_cast<u16*>(&h);
}
__device__ __forceinline__ float blo(u32 u) { return __uint_as_float(u << 16); }
__device__ __forceinline__ float bhi(u32 u) { return __uint_as_float(u & 0xffff0000u); }

struct P {
    const float* x; const int* batch; const float* info;
    const int* src; const int* dst;
    const float *Wl0, *Wr0, *b0, *Wl1, *Wr1, *b1, *Wl2, *Wr2, *b2;
    const float *Wfc1, *bfc1, *Wfc2, *bfc2;
    float* out;
    int* grescnt; u32* ebin; int* start; u16* xb;
    u16 *WT0, *WT1, *WT2;
    float *iQl0, *iQr0, *iQl1, *iQr1, *iQl2, *iQr2;
    int* cnt; u16* csr;
    u16 *h1, *h2, *h3, *zlp, *zq;
    float* gpart;
};

// ---------------- phase pieces (R12-proven bodies) ----------------

__device__ void sec_binA(int vb, const int* __restrict__ src, const int* __restrict__ dst,
                         int* __restrict__ grescnt, u32* __restrict__ ebin, char* smem) {
    u32* pairs = (u32*)smem;
    int* lcnt  = (int*)(smem + EPB * 4);
    int t = threadIdx.x;
    int base = vb * EPB;
    lcnt[t] = 0;
    __syncthreads();
    for (int j = t; j < EPB; j += 256) {
        int e = base + j;
        int d = dst[e];
        int s = src[e];
        pairs[j] = ((u32)(d & 255) << 24) | ((u32)(d >> 8) << 16) | (u32)s;
        atomicAdd(&lcnt[d >> 8], 1);
    }
    __syncthreads();
    int myCnt = lcnt[t];
    int myBase = atomicAdd(&grescnt[t * 16], myCnt);   // padded: 1 counter per 64B line
    __syncthreads();
    lcnt[t] = myBase;
    __syncthreads();
    for (int j = t; j < EPB; j += 256) {
        u32 pr = pairs[j];
        int r = (pr >> 16) & 255;
        int pos = atomicAdd(&lcnt[r], 1);
        if (pos < (1 << RCAPLOG)) ebin[(r << RCAPLOG) + pos] = pr;
    }
}

__device__ void sec_starts(int vb, const int* __restrict__ batch, int* __restrict__ start) {
    int i = vb * 256 + threadIdx.x;
    if (i >= NN) return;
    int b = batch[i];
    if (i == 0) { for (int g = 0; g <= b; ++g) start[g] = 0; }
    else {
        int p = batch[i - 1];
        if (p != b) for (int g = p + 1; g <= b; ++g) start[g] = i;
    }
    if (i == NN - 1) { for (int g = b + 1; g <= NG; ++g) start[g] = NN; }
}

__device__ void sec_cast(int vb, const float* __restrict__ x, u16* __restrict__ xb) {
    int tid = vb * 256 + threadIdx.x;
    if (tid >= NN * DF / 4) return;
    float4 v = *(const float4*)&x[tid * 4];
    ushort4 o;
    o.x = f2b(v.x); o.y = f2b(v.y); o.z = f2b(v.z); o.w = f2b(v.w);
    *(ushort4*)&xb[tid * 4] = o;
}

__device__ void sec_wt(int rel, const float* __restrict__ Wl, const float* __restrict__ Wr,
                       u16* __restrict__ WT, int K) {
    int tid = rel * 256 + threadIdx.x;
    if (tid >= 256 * K) return;
    int n = tid / K;
    int k = tid - n * K;
    float v = (n < CO) ? Wl[k * CO + n] : Wr[k * CO + (n - CO)];
    WT[tid] = f2b(v);
}

__device__ void sec_infow(int g, const float* __restrict__ info,
                          const float* __restrict__ Wl, const float* __restrict__ Wr,
                          const float* __restrict__ bias, int Ktop,
                          float* __restrict__ iQl, float* __restrict__ iQr) {
    int t = threadIdx.x;
    int c = t & 127;
    int sel = t >> 7;
    const float* W = sel ? Wr : Wl;
    float a = sel ? bias[c] : 0.0f;
    for (int d = 0; d < DI; ++d)
        a += info[g * DI + d] * W[(Ktop + d) * CO + c];
    (sel ? iQr : iQl)[g * CO + c] = a;
}

// ---------------- kernels ----------------

// prep: binA | starts | cast | wt x3 | infow x3  (R12 layout)
#define PB_BIN    256
#define PB_STARTS 196
#define PB_CAST   4688
#define PB_WT     352
#define PB_INFO   1500
#define PREP_GRID (PB_BIN + PB_STARTS + PB_CAST + PB_WT + PB_INFO)

__global__ __launch_bounds__(256) void k_prep(P p) {
    __shared__ __align__(16) char smem[EPB * 4 + 1024];
    int blk = blockIdx.x;
    if (blk < PB_BIN) { sec_binA(blk, p.src, p.dst, p.grescnt, p.ebin, smem); return; }
    blk -= PB_BIN;
    if (blk < PB_STARTS) { sec_starts(blk, p.batch, p.start); return; }
    blk -= PB_STARTS;
    if (blk < PB_CAST) { sec_cast(blk, p.x, p.xb); return; }
    blk -= PB_CAST;
    if (blk < PB_WT) {
        if (blk < 96)       sec_wt(blk, p.Wl0, p.Wr0, p.WT0, 96);
        else if (blk < 224) sec_wt(blk - 96, p.Wl1, p.Wr1, p.WT1, 128);
        else                sec_wt(blk - 224, p.Wl2, p.Wr2, p.WT2, 128);
        return;
    }
    blk -= PB_WT;
    if (blk < 500)       sec_infow(blk, p.info, p.Wl0, p.Wr0, p.b0, 96,  p.iQl0, p.iQr0);
    else if (blk < 1000) sec_infow(blk - 500, p.info, p.Wl1, p.Wr1, p.b1, 128, p.iQl1, p.iQr1);
    else                 sec_infow(blk - 1000, p.info, p.Wl2, p.Wr2, p.b2, 128, p.iQl2, p.iQr2);
}

// binB: per-range CSR fill (separate dispatch — R16 showed fusing it costs more)
__global__ __launch_bounds__(256) void k_binB(P p) {
    __shared__ int lcnt[256];
    int r = blockIdx.x;
    int t = threadIdx.x;
    lcnt[t] = 0;
    __syncthreads();
    int total = p.grescnt[r * 16];
    if (total > (1 << RCAPLOG)) total = 1 << RCAPLOG;
    for (int j = t; j < total; j += 256) {
        u32 pr = p.ebin[(r << RCAPLOG) + j];
        int dloc = pr >> 24;
        int rank = atomicAdd(&lcnt[dloc], 1);
        int node = (r << 8) + dloc;
        if (rank < (1 << CAPLOG)) p.csr[(node << CAPLOG) + rank] = (u16)(pr & 0xffff);
    }
    __syncthreads();
    int node = (r << 8) + t;
    if (node < NN) p.cnt[node] = lcnt[t];
}

// MFMA GEMM + fused combine (R12-proven, standalone dispatch)
template<int K>
__global__ __launch_bounds__(256) void k_mfma(P p, const u16* __restrict__ A,
                                              const u16* __restrict__ WTg,
                                              const float* __restrict__ iQl,
                                              const float* __restrict__ iQr) {
    constexpr int PITCH = K + 8;
    __shared__ short lds[256 * PITCH];

    int tid  = threadIdx.x;
    int w    = tid >> 6;
    int lane = tid & 63;
    int quad = lane >> 4;
    int l15  = lane & 15;

    constexpr int CH = 256 * K / 8;
    const uint4* wp = (const uint4*)WTg;
    for (int c = tid; c < CH; c += 256) {
        int n  = c / (K / 8);
        int ko = (c - n * (K / 8)) * 8;
        *(uint4*)&lds[n * PITCH + ko] = wp[c];
    }
    __syncthreads();

    int i0 = blockIdx.x * 128 + w * 32;
    int r0 = i0 + l15;       if (r0 >= NN) r0 = NN - 1;
    int r1 = i0 + 16 + l15;  if (r1 >= NN) r1 = NN - 1;
    const short* A0 = (const short*)A + (size_t)r0 * K;
    const short* A1 = (const short*)A + (size_t)r1 * K;

    f32x4 acc[2][16];
#pragma unroll
    for (int rt = 0; rt < 2; ++rt)
#pragma unroll
        for (int ct = 0; ct < 16; ++ct)
            acc[rt][ct] = (f32x4){0.f, 0.f, 0.f, 0.f};

#pragma unroll
    for (int ks = 0; ks < K / 32; ++ks) {
        int ka = ks * 32 + quad * 8;
        bf16x8 a0 = *(const bf16x8*)(A0 + ka);
        bf16x8 a1 = *(const bf16x8*)(A1 + ka);
#pragma unroll
        for (int ct = 0; ct < 16; ++ct) {
            bf16x8 b = *(const bf16x8*)&lds[(ct * 16 + l15) * PITCH + ka];
            acc[0][ct] = __builtin_amdgcn_mfma_f32_16x16x32_bf16(a0, b, acc[0][ct], 0, 0, 0);
            acc[1][ct] = __builtin_amdgcn_mfma_f32_16x16x32_bf16(a1, b, acc[1][ct], 0, 0, 0);
        }
    }

#pragma unroll
    for (int rt = 0; rt < 2; ++rt) {
#pragma unroll
        for (int reg = 0; reg < 4; ++reg) {
            int row = i0 + rt * 16 + quad * 4 + reg;
            if (row < NN) {
                int b = p.batch[row];
                const float* ql = &iQl[b * CO];
                const float* qr = &iQr[b * CO];
                u16* lp = p.zlp + (size_t)row * CO;
                u16* qp = p.zq  + (size_t)row * CO;
#pragma unroll
                for (int ct = 0; ct < 8; ++ct) {
                    int col = ct * 16 + l15;
                    lp[col] = f2b(acc[rt][ct][reg] + ql[col]);
                }
#pragma unroll
                for (int ct = 8; ct < 16; ++ct) {
                    int col = ct * 16 + l15 - 128;
                    qp[col] = f2b(acc[rt][ct][reg] + qr[col]);
                }
            }
        }
    }
}

__device__ __forceinline__ void acc8(float* a, const uint4& u) {
    a[0] += blo(u.x); a[1] += bhi(u.x);
    a[2] += blo(u.y); a[3] += bhi(u.y);
    a[4] += blo(u.z); a[5] += bhi(u.z);
    a[6] += blo(u.w); a[7] += bhi(u.w);
}

__device__ void sec_gather(int vb, const u32* __restrict__ zlp, const u32* __restrict__ zq,
                           const int* __restrict__ cnt, const u16* __restrict__ csr,
                           u32* __restrict__ hout) {
    int wave = threadIdx.x >> 6;
    int lane = threadIdx.x & 63;
    int q    = lane >> 4;
    int l16  = lane & 15;
    int i = vb * 4 + wave;
    if (i >= NN) return;
    int deg = cnt[i];
    int degc = min(deg, 1 << CAPLOG);
    int s0 = i << CAPLOG;
    int s1 = s0 + degc;

    const uint4* Z = (const uint4*)zlp;

    float a[8] = {0,0,0,0,0,0,0,0};
    float b[8] = {0,0,0,0,0,0,0,0};
    float c[8] = {0,0,0,0,0,0,0,0};
    float d[8] = {0,0,0,0,0,0,0,0};

    int e = s0;
    for (; e + 15 < s1; e += 16) {
        int n0 = csr[e + q];
        int n1 = csr[e + 4 + q];
        int n2 = csr[e + 8 + q];
        int n3 = csr[e + 12 + q];
        uint4 u0 = Z[(size_t)n0 * 16 + l16];
        uint4 u1 = Z[(size_t)n1 * 16 + l16];
        uint4 u2 = Z[(size_t)n2 * 16 + l16];
        uint4 u3 = Z[(size_t)n3 * 16 + l16];
        acc8(a, u0); acc8(b, u1); acc8(c, u2); acc8(d, u3);
    }
    for (; e < s1; e += 4) {
        if (e + q < s1) {
            int n0 = csr[e + q];
            uint4 u0 = Z[(size_t)n0 * 16 + l16];
            acc8(a, u0);
        }
    }
#pragma unroll
    for (int j = 0; j < 8; ++j) {
        a[j] += b[j] + c[j] + d[j];
        a[j] += __shfl_xor(a[j], 16);
        a[j] += __shfl_xor(a[j], 32);
    }
    if (q == 0) {
        float r = 1.0f / fmaxf((float)deg, 1.0f);
        uint4 qq = ((const uint4*)zq)[(size_t)i * 16 + l16];
        uint4 o;
        o.x = (u32)f2b(a[0] * r + blo(qq.x)) | ((u32)f2b(a[1] * r + bhi(qq.x)) << 16);
        o.y = (u32)f2b(a[2] * r + blo(qq.y)) | ((u32)f2b(a[3] * r + bhi(qq.y)) << 16);
        o.z = (u32)f2b(a[4] * r + blo(qq.z)) | ((u32)f2b(a[5] * r + bhi(qq.z)) << 16);
        o.w = (u32)f2b(a[6] * r + blo(qq.w)) | ((u32)f2b(a[7] * r + bhi(qq.w)) << 16);
        ((uint4*)hout)[(size_t)i * 16 + l16] = o;
    }
}

// partial pool of one h-buffer into gpart (R16-verified). Low-resource: 2KB LDS.
__device__ void sec_poolpart(int gr, const u32* __restrict__ hb, const int* __restrict__ start,
                             float* __restrict__ gpart, int off) {
    __shared__ float s_part[4][128];
    int t = threadIdx.x, w = t >> 6, lane = t & 63;
    int s = start[gr], e = start[gr + 1];
    float mlo = -FLT_MAX, mhi = -FLT_MAX;
    for (int n = s + w; n < e; n += 4) {
        u32 v = hb[(size_t)n * 64 + lane];
        mlo = fmaxf(mlo, blo(v)); mhi = fmaxf(mhi, bhi(v));
    }
    s_part[w][2 * lane]     = mlo;
    s_part[w][2 * lane + 1] = mhi;
    __syncthreads();
    if (t < 128) {
        float m = fmaxf(fmaxf(s_part[0][t], s_part[1][t]), fmaxf(s_part[2][t], s_part[3][t]));
        gpart[gr * 256 + off + t] = m;
    }
}

// plain gather (layer-0 output)
__global__ __launch_bounds__(256) void k_g(P p, const u16* hout) {
    sec_gather(blockIdx.x, (const u32*)p.zlp, (const u32*)p.zq, p.cnt, p.csr, (u32*)hout);
}

// gather || poolpart of an already-finished h-buffer (compatible resource profiles)
__global__ __launch_bounds__(256) void k_gp(P p, const u16* hout, const u16* hpool, int off) {
    int blk = blockIdx.x;
    if (blk < GGATH) sec_gather(blk, (const u32*)p.zlp, (const u32*)p.zq, p.cnt, p.csr, (u32*)hout);
    else             sec_poolpart(blk - GGATH, (const u32*)hpool, p.start, p.gpart, off);
}

// final: pool h3 + FC head (gpart supplies cols 0..255) — R16-verified
__global__ __launch_bounds__(256) void k_pf(P p) {
    __shared__ float s_g[F1I];
    __shared__ float s_z[F1O];
    __shared__ float s_part[4][128];
    int gr = blockIdx.x;
    int t = threadIdx.x, w = t >> 6, lane = t & 63;
    int s = p.start[gr], e = p.start[gr + 1];
    const u32* hb = (const u32*)p.h3;
    float mlo = -FLT_MAX, mhi = -FLT_MAX;
    for (int n = s + w; n < e; n += 4) {
        u32 v = hb[(size_t)n * 64 + lane];
        mlo = fmaxf(mlo, blo(v)); mhi = fmaxf(mhi, bhi(v));
    }
    s_part[w][2 * lane]     = mlo;
    s_part[w][2 * lane + 1] = mhi;
    s_g[t] = p.gpart[gr * 256 + t];
    __syncthreads();
    if (t < 128)
        s_g[256 + t] = fmaxf(fmaxf(s_part[0][t], s_part[1][t]),
                             fmaxf(s_part[2][t], s_part[3][t]));
    __syncthreads();
    if (t < F1O) {
        float acc = p.bfc1[t];
        for (int k = 0; k < F1I; ++k) acc += s_g[k] * p.Wfc1[k * F1O + t];
        s_z[t] = fmaxf(acc, 0.0f);
    }
    __syncthreads();
    if (t < F2O) {
        float a = p.bfc2[t];
        for (int k = 0; k < F1O; ++k) a += s_z[k] * p.Wfc2[k * F2O + t];
        p.out[gr * F2O + t] = a;
    }
}

extern "C" void kernel_launch(void* const* d_in, const int* in_sizes, int n_in,
                              void* d_out, int out_size, void* d_ws, size_t ws_size,
                              hipStream_t stream) {
    const int* eidx = (const int*)d_in[1];

    char* W = (char*)d_ws;
    P p;
    p.x     = (const float*)d_in[0];
    p.batch = (const int*)d_in[2];
    p.info  = (const float*)d_in[3];
    p.src   = eidx;
    p.dst   = eidx + NE;
    p.Wl0 = (const float*)d_in[4];  p.Wr0 = (const float*)d_in[5];  p.b0 = (const float*)d_in[6];
    p.Wl1 = (const float*)d_in[7];  p.Wr1 = (const float*)d_in[8];  p.b1 = (const float*)d_in[9];
    p.Wl2 = (const float*)d_in[10]; p.Wr2 = (const float*)d_in[11]; p.b2 = (const float*)d_in[12];
    p.Wfc1 = (const float*)d_in[13]; p.bfc1 = (const float*)d_in[14];
    p.Wfc2 = (const float*)d_in[15]; p.bfc2 = (const float*)d_in[16];
    p.out = (float*)d_out;

    p.xb     = (u16*)(W + 0);             // 50000*96 bf16
    p.h1     = (u16*)(W + 9600000);       // 50000*128 bf16 each
    p.h2     = (u16*)(W + 22400000);
    p.h3     = (u16*)(W + 35200000);
    p.zlp    = (u16*)(W + 48000000);
    p.zq     = (u16*)(W + 60800000);
    p.WT0    = (u16*)(W + 73600000);
    p.WT1    = (u16*)(W + 73649152);
    p.WT2    = (u16*)(W + 73714688);
    p.iQl0   = (float*)(W + 73780224);
    p.iQr0   = (float*)(W + 74036224);
    p.iQl1   = (float*)(W + 74292224);
    p.iQr1   = (float*)(W + 74548224);
    p.iQl2   = (float*)(W + 74804224);
    p.iQr2   = (float*)(W + 75060224);
    p.start  = (int*)(W + 75316224);      // NG+1
    p.cnt    = (int*)(W + 75318272);      // NN
    p.csr    = (u16*)(W + 75518336);      // NN*128 u16 = 12.8 MB
    p.ebin   = (u32*)(W + 88318336);      // 256*8192 u32 = 8 MB
    p.grescnt= (int*)(W + 96706560);      // 256 x16 padded ints (16 KB)
    p.gpart  = (float*)(W + 96722944);    // 500 x 256 f32 (512 KB)

    hipMemsetAsync(p.grescnt, 0, 256 * 16 * sizeof(int), stream);
    k_prep<<<PREP_GRID, 256, 0, stream>>>(p);
    k_binB<<<NRANGE, 256, 0, stream>>>(p);

    k_mfma<96><<<GGEMM, 256, 0, stream>>>(p, p.xb, p.WT0, p.iQl0, p.iQr0);
    k_g<<<GGATH, 256, 0, stream>>>(p, p.h1);

    k_mfma<128><<<GGEMM, 256, 0, stream>>>(p, p.h1, p.WT1, p.iQl1, p.iQr1);
    k_gp<<<GGATH + NG, 256, 0, stream>>>(p, p.h2, p.h1, 0);     // gather h2 || pool h1

    k_mfma<128><<<GGEMM, 256, 0, stream>>>(p, p.h2, p.WT2, p.iQl2, p.iQr2);
    k_gp<<<GGATH + NG, 256, 0, stream>>>(p, p.h3, p.h2, 128);   // gather h3 || pool h2

    k_pf<<<NG, 256, 0, stream>>>(p);
}

// Round 18
// 301.662 us; speedup vs baseline: 3.6540x; 1.0384x over previous
//
#include <hip/hip_runtime.h>
#include <hip/hip_bf16.h>
#include <float.h>

#define NN 50000
#define NE 800000
#define DF 96
#define DI 32
#define CO 128
#define NG 500
#define F1I 384
#define F1O 160
#define F2O 10
#define CAPLOG 7        // csr bucket capacity 128; max observed deg ~45
#define NRANGE 196      // dst>>8 ranges
#define EPB 3125        // edges per binA block (256 blocks)
#define RCAPLOG 13      // ebin region capacity 8192 (mean 4082)
#define GGEMM 391       // ceil(NN/128)
#define GGATH 12500     // ceil(NN/4)

typedef unsigned int  u32;
typedef unsigned short u16;
typedef short bf16x8 __attribute__((ext_vector_type(8)));
typedef float f32x4  __attribute__((ext_vector_type(4)));

__device__ __forceinline__ u16 f2b(float f) {
    __hip_bfloat16 h = __float2bfloat16(f);
    return *reinterpret_cast<u16*>(&h);
}
__device__ __forceinline__ float blo(u32 u) { return __uint_as_float(u << 16); }
__device__ __forceinline__ float bhi(u32 u) { return __uint_as_float(u & 0xffff0000u); }

struct P {
    const float* x; const int* batch; const float* info;
    const int* src; const int* dst;
    const float *Wl0, *Wr0, *b0, *Wl1, *Wr1, *b1, *Wl2, *Wr2, *b2;
    const float *Wfc1, *bfc1, *Wfc2, *bfc2;
    float* out;
    int* grescnt; u32* ebin; int* start; u16* xb;
    u16 *WT0, *WT1, *WT2;
    float *iQl0, *iQr0, *iQl1, *iQr1, *iQl2, *iQr2;
    int* cnt; u16* csr;
    u16 *h1, *h2, *h3, *zlp, *zq;
};

// ---------------- phase pieces (R12-proven bodies) ----------------

__device__ void sec_binA(int vb, const int* __restrict__ src, const int* __restrict__ dst,
                         int* __restrict__ grescnt, u32* __restrict__ ebin, char* smem) {
    u32* pairs = (u32*)smem;
    int* lcnt  = (int*)(smem + EPB * 4);
    int t = threadIdx.x;
    int base = vb * EPB;
    lcnt[t] = 0;
    __syncthreads();
    for (int j = t; j < EPB; j += 256) {
        int e = base + j;
        int d = dst[e];
        int s = src[e];
        pairs[j] = ((u32)(d & 255) << 24) | ((u32)(d >> 8) << 16) | (u32)s;
        atomicAdd(&lcnt[d >> 8], 1);
    }
    __syncthreads();
    int myCnt = lcnt[t];
    int myBase = atomicAdd(&grescnt[t * 16], myCnt);   // padded: 1 counter per 64B line
    __syncthreads();
    lcnt[t] = myBase;
    __syncthreads();
    for (int j = t; j < EPB; j += 256) {
        u32 pr = pairs[j];
        int r = (pr >> 16) & 255;
        int pos = atomicAdd(&lcnt[r], 1);
        if (pos < (1 << RCAPLOG)) ebin[(r << RCAPLOG) + pos] = pr;
    }
}

__device__ void sec_starts(int vb, const int* __restrict__ batch, int* __restrict__ start) {
    int i = vb * 256 + threadIdx.x;
    if (i >= NN) return;
    int b = batch[i];
    if (i == 0) { for (int g = 0; g <= b; ++g) start[g] = 0; }
    else {
        int p = batch[i - 1];
        if (p != b) for (int g = p + 1; g <= b; ++g) start[g] = i;
    }
    if (i == NN - 1) { for (int g = b + 1; g <= NG; ++g) start[g] = NN; }
}

__device__ void sec_binB(int r, const u32* __restrict__ ebin, const int* __restrict__ grescnt,
                         int* __restrict__ cnt, u16* __restrict__ csr, char* smem) {
    int* lcnt = (int*)smem;
    int t = threadIdx.x;
    lcnt[t] = 0;
    __syncthreads();
    int total = grescnt[r * 16];
    if (total > (1 << RCAPLOG)) total = 1 << RCAPLOG;
    for (int j = t; j < total; j += 256) {
        u32 p = ebin[(r << RCAPLOG) + j];
        int dloc = p >> 24;
        int rank = atomicAdd(&lcnt[dloc], 1);
        int node = (r << 8) + dloc;
        if (rank < (1 << CAPLOG)) csr[(node << CAPLOG) + rank] = (u16)(p & 0xffff);
    }
    __syncthreads();
    int node = (r << 8) + t;
    if (node < NN) cnt[node] = lcnt[t];
}

__device__ void sec_cast(int vb, const float* __restrict__ x, u16* __restrict__ xb) {
    int tid = vb * 256 + threadIdx.x;
    if (tid >= NN * DF / 4) return;
    float4 v = *(const float4*)&x[tid * 4];
    ushort4 o;
    o.x = f2b(v.x); o.y = f2b(v.y); o.z = f2b(v.z); o.w = f2b(v.w);
    *(ushort4*)&xb[tid * 4] = o;
}

__device__ void sec_wt(int rel, const float* __restrict__ Wl, const float* __restrict__ Wr,
                       u16* __restrict__ WT, int K) {
    int tid = rel * 256 + threadIdx.x;
    if (tid >= 256 * K) return;
    int n = tid / K;
    int k = tid - n * K;
    float v = (n < CO) ? Wl[k * CO + n] : Wr[k * CO + (n - CO)];
    WT[tid] = f2b(v);
}

__device__ void sec_infow(int g, const float* __restrict__ info,
                          const float* __restrict__ Wl, const float* __restrict__ Wr,
                          const float* __restrict__ bias, int Ktop,
                          float* __restrict__ iQl, float* __restrict__ iQr) {
    int t = threadIdx.x;
    int c = t & 127;
    int sel = t >> 7;
    const float* W = sel ? Wr : Wl;
    float a = sel ? bias[c] : 0.0f;
    for (int d = 0; d < DI; ++d)
        a += info[g * DI + d] * W[(Ktop + d) * CO + c];
    (sel ? iQr : iQl)[g * CO + c] = a;
}

template<int K>
__device__ void sec_mfma(int vb, const u16* __restrict__ A, const u16* __restrict__ WTg,
                         const int* __restrict__ batch,
                         const float* __restrict__ iQl, const float* __restrict__ iQr,
                         u16* __restrict__ zlp, u16* __restrict__ zq, char* smem) {
    constexpr int PITCH = K + 8;
    short* lds = (short*)smem;

    int tid  = threadIdx.x;
    int w    = tid >> 6;
    int lane = tid & 63;
    int quad = lane >> 4;
    int l15  = lane & 15;

    constexpr int CH = 256 * K / 8;
    const uint4* wp = (const uint4*)WTg;
    for (int c = tid; c < CH; c += 256) {
        int n  = c / (K / 8);
        int ko = (c - n * (K / 8)) * 8;
        *(uint4*)&lds[n * PITCH + ko] = wp[c];
    }
    __syncthreads();

    int i0 = vb * 128 + w * 32;
    int r0 = i0 + l15;       if (r0 >= NN) r0 = NN - 1;
    int r1 = i0 + 16 + l15;  if (r1 >= NN) r1 = NN - 1;
    const short* A0 = (const short*)A + (size_t)r0 * K;
    const short* A1 = (const short*)A + (size_t)r1 * K;

    f32x4 acc[2][16];
#pragma unroll
    for (int rt = 0; rt < 2; ++rt)
#pragma unroll
        for (int ct = 0; ct < 16; ++ct)
            acc[rt][ct] = (f32x4){0.f, 0.f, 0.f, 0.f};

#pragma unroll
    for (int ks = 0; ks < K / 32; ++ks) {
        int ka = ks * 32 + quad * 8;
        bf16x8 a0 = *(const bf16x8*)(A0 + ka);
        bf16x8 a1 = *(const bf16x8*)(A1 + ka);
#pragma unroll
        for (int ct = 0; ct < 16; ++ct) {
            bf16x8 b = *(const bf16x8*)&lds[(ct * 16 + l15) * PITCH + ka];
            acc[0][ct] = __builtin_amdgcn_mfma_f32_16x16x32_bf16(a0, b, acc[0][ct], 0, 0, 0);
            acc[1][ct] = __builtin_amdgcn_mfma_f32_16x16x32_bf16(a1, b, acc[1][ct], 0, 0, 0);
        }
    }

#pragma unroll
    for (int rt = 0; rt < 2; ++rt) {
#pragma unroll
        for (int reg = 0; reg < 4; ++reg) {
            int row = i0 + rt * 16 + quad * 4 + reg;
            if (row < NN) {
                int b = batch[row];
                const float* ql = &iQl[b * CO];
                const float* qr = &iQr[b * CO];
                u16* lp = zlp + (size_t)row * CO;
                u16* qp = zq  + (size_t)row * CO;
#pragma unroll
                for (int ct = 0; ct < 8; ++ct) {
                    int col = ct * 16 + l15;
                    lp[col] = f2b(acc[rt][ct][reg] + ql[col]);
                }
#pragma unroll
                for (int ct = 8; ct < 16; ++ct) {
                    int col = ct * 16 + l15 - 128;
                    qp[col] = f2b(acc[rt][ct][reg] + qr[col]);
                }
            }
        }
    }
}

__device__ __forceinline__ void acc8(float* a, const uint4& u) {
    a[0] += blo(u.x); a[1] += bhi(u.x);
    a[2] += blo(u.y); a[3] += bhi(u.y);
    a[4] += blo(u.z); a[5] += bhi(u.z);
    a[6] += blo(u.w); a[7] += bhi(u.w);
}

// ---------------- kernels ----------------

// prep: binA | starts | cast | wt x3 | infow x3  (R12 layout, verbatim)
#define PB_BIN    256
#define PB_STARTS 196
#define PB_CAST   4688
#define PB_WT     352
#define PB_INFO   1500
#define PREP_GRID (PB_BIN + PB_STARTS + PB_CAST + PB_WT + PB_INFO)

__global__ __launch_bounds__(256) void k_prep(P p) {
    __shared__ __align__(16) char smem[EPB * 4 + 1024];
    int blk = blockIdx.x;
    if (blk < PB_BIN) { sec_binA(blk, p.src, p.dst, p.grescnt, p.ebin, smem); return; }
    blk -= PB_BIN;
    if (blk < PB_STARTS) { sec_starts(blk, p.batch, p.start); return; }
    blk -= PB_STARTS;
    if (blk < PB_CAST) { sec_cast(blk, p.x, p.xb); return; }
    blk -= PB_CAST;
    if (blk < PB_WT) {
        if (blk < 96)       sec_wt(blk, p.Wl0, p.Wr0, p.WT0, 96);
        else if (blk < 224) sec_wt(blk - 96, p.Wl1, p.Wr1, p.WT1, 128);
        else                sec_wt(blk - 224, p.Wl2, p.Wr2, p.WT2, 128);
        return;
    }
    blk -= PB_WT;
    if (blk < 500)       sec_infow(blk, p.info, p.Wl0, p.Wr0, p.b0, 96,  p.iQl0, p.iQr0);
    else if (blk < 1000) sec_infow(blk - 500, p.info, p.Wl1, p.Wr1, p.b1, 128, p.iQl1, p.iQr1);
    else                 sec_infow(blk - 1000, p.info, p.Wl2, p.Wr2, p.b2, 128, p.iQl2, p.iQr2);
}

// l0: binB (196) || mfma<96> (391) — independent after prep; union profile ≈ mfma alone.
// (R16 validated this packing; its regression came from the mfma||pool kernels, not this.)
__global__ __launch_bounds__(256) void k_l0(P p) {
    __shared__ __align__(16) char smem[256 * (96 + 8) * 2];   // 53,248 B (mfma<96> footprint)
    int blk = blockIdx.x;
    if (blk < NRANGE) sec_binB(blk, p.ebin, p.grescnt, p.cnt, p.csr, smem);
    else              sec_mfma<96>(blk - NRANGE, p.xb, p.WT0, p.batch, p.iQl0, p.iQr0,
                                   p.zlp, p.zq, smem);
}

// standalone mfma<128> (R12-proven)
__global__ __launch_bounds__(256) void k_mfma128(P p, const u16* __restrict__ A,
                                                 const u16* __restrict__ WTg,
                                                 const float* __restrict__ iQl,
                                                 const float* __restrict__ iQr) {
    __shared__ __align__(16) char smem[256 * (128 + 8) * 2];
    sec_mfma<128>(blockIdx.x, A, WTg, p.batch, iQl, iQr, p.zlp, p.zq, smem);
}

// gather-mean (R12-proven quarter-wave uint4)
__global__ __launch_bounds__(256) void k_g(P p, u16* hout) {
    int wave = threadIdx.x >> 6;
    int lane = threadIdx.x & 63;
    int q    = lane >> 4;
    int l16  = lane & 15;
    int i = blockIdx.x * 4 + wave;
    if (i >= NN) return;
    int deg = p.cnt[i];
    int degc = min(deg, 1 << CAPLOG);
    int s0 = i << CAPLOG;
    int s1 = s0 + degc;

    const uint4* Z = (const uint4*)p.zlp;
    const u16* csr = p.csr;

    float a[8] = {0,0,0,0,0,0,0,0};
    float b[8] = {0,0,0,0,0,0,0,0};
    float c[8] = {0,0,0,0,0,0,0,0};
    float d[8] = {0,0,0,0,0,0,0,0};

    int e = s0;
    for (; e + 15 < s1; e += 16) {
        int n0 = csr[e + q];
        int n1 = csr[e + 4 + q];
        int n2 = csr[e + 8 + q];
        int n3 = csr[e + 12 + q];
        uint4 u0 = Z[(size_t)n0 * 16 + l16];
        uint4 u1 = Z[(size_t)n1 * 16 + l16];
        uint4 u2 = Z[(size_t)n2 * 16 + l16];
        uint4 u3 = Z[(size_t)n3 * 16 + l16];
        acc8(a, u0); acc8(b, u1); acc8(c, u2); acc8(d, u3);
    }
    for (; e < s1; e += 4) {
        if (e + q < s1) {
            int n0 = csr[e + q];
            uint4 u0 = Z[(size_t)n0 * 16 + l16];
            acc8(a, u0);
        }
    }
#pragma unroll
    for (int j = 0; j < 8; ++j) {
        a[j] += b[j] + c[j] + d[j];
        a[j] += __shfl_xor(a[j], 16);
        a[j] += __shfl_xor(a[j], 32);
    }
    if (q == 0) {
        float r = 1.0f / fmaxf((float)deg, 1.0f);
        uint4 qq = ((const uint4*)p.zq)[(size_t)i * 16 + l16];
        uint4 o;
        o.x = (u32)f2b(a[0] * r + blo(qq.x)) | ((u32)f2b(a[1] * r + bhi(qq.x)) << 16);
        o.y = (u32)f2b(a[2] * r + blo(qq.y)) | ((u32)f2b(a[3] * r + bhi(qq.y)) << 16);
        o.z = (u32)f2b(a[4] * r + blo(qq.z)) | ((u32)f2b(a[5] * r + bhi(qq.z)) << 16);
        o.w = (u32)f2b(a[6] * r + blo(qq.w)) | ((u32)f2b(a[7] * r + bhi(qq.w)) << 16);
        ((uint4*)hout)[(size_t)i * 16 + l16] = o;
    }
}

// fused pool + FC head (R12-proven 384-thread version)
__global__ __launch_bounds__(384) void k_poolfc(P p) {
    __shared__ float s_part[6][128];
    __shared__ float s_g[F1I];
    __shared__ float s_z[F1O];
    int gr = blockIdx.x;
    int t  = threadIdx.x;
    int w    = t >> 6;
    int lane = t & 63;
    int buf  = w % 3;
    int half = w / 3;
    const u32* hb = (buf == 0) ? (const u32*)p.h1 : (buf == 1) ? (const u32*)p.h2 : (const u32*)p.h3;
    int s = p.start[gr], e = p.start[gr + 1];
    int mid = (s + e) >> 1;
    int n0 = half ? mid : s;
    int n1 = half ? e : mid;

    float mlo[4], mhi[4];
#pragma unroll
    for (int j = 0; j < 4; ++j) { mlo[j] = -FLT_MAX; mhi[j] = -FLT_MAX; }
    int n = n0;
    for (; n + 3 < n1; n += 4) {
        u32 v0 = hb[(size_t)(n + 0) * 64 + lane];
        u32 v1 = hb[(size_t)(n + 1) * 64 + lane];
        u32 v2 = hb[(size_t)(n + 2) * 64 + lane];
        u32 v3 = hb[(size_t)(n + 3) * 64 + lane];
        mlo[0] = fmaxf(mlo[0], blo(v0)); mhi[0] = fmaxf(mhi[0], bhi(v0));
        mlo[1] = fmaxf(mlo[1], blo(v1)); mhi[1] = fmaxf(mhi[1], bhi(v1));
        mlo[2] = fmaxf(mlo[2], blo(v2)); mhi[2] = fmaxf(mhi[2], bhi(v2));
        mlo[3] = fmaxf(mlo[3], blo(v3)); mhi[3] = fmaxf(mhi[3], bhi(v3));
    }
    for (; n < n1; ++n) {
        u32 v0 = hb[(size_t)n * 64 + lane];
        mlo[0] = fmaxf(mlo[0], blo(v0)); mhi[0] = fmaxf(mhi[0], bhi(v0));
    }
    float lo = fmaxf(fmaxf(mlo[0], mlo[1]), fmaxf(mlo[2], mlo[3]));
    float hi = fmaxf(fmaxf(mhi[0], mhi[1]), fmaxf(mhi[2], mhi[3]));
    s_part[w][2 * lane]     = lo;
    s_part[w][2 * lane + 1] = hi;
    __syncthreads();
    {
        int buf2 = t >> 7, cc = t & 127;
        s_g[t] = fmaxf(s_part[buf2][cc], s_part[buf2 + 3][cc]);
    }
    __syncthreads();
    if (t < F1O) {
        float acc = p.bfc1[t];
        for (int k = 0; k < F1I; ++k) acc += s_g[k] * p.Wfc1[k * F1O + t];
        s_z[t] = fmaxf(acc, 0.0f);
    }
    __syncthreads();
    if (t < F2O) {
        float a = p.bfc2[t];
        for (int k = 0; k < F1O; ++k) a += s_z[k] * p.Wfc2[k * F2O + t];
        p.out[gr * F2O + t] = a;
    }
}

extern "C" void kernel_launch(void* const* d_in, const int* in_sizes, int n_in,
                              void* d_out, int out_size, void* d_ws, size_t ws_size,
                              hipStream_t stream) {
    const int* eidx = (const int*)d_in[1];

    char* W = (char*)d_ws;
    P p;
    p.x     = (const float*)d_in[0];
    p.batch = (const int*)d_in[2];
    p.info  = (const float*)d_in[3];
    p.src   = eidx;
    p.dst   = eidx + NE;
    p.Wl0 = (const float*)d_in[4];  p.Wr0 = (const float*)d_in[5];  p.b0 = (const float*)d_in[6];
    p.Wl1 = (const float*)d_in[7];  p.Wr1 = (const float*)d_in[8];  p.b1 = (const float*)d_in[9];
    p.Wl2 = (const float*)d_in[10]; p.Wr2 = (const float*)d_in[11]; p.b2 = (const float*)d_in[12];
    p.Wfc1 = (const float*)d_in[13]; p.bfc1 = (const float*)d_in[14];
    p.Wfc2 = (const float*)d_in[15]; p.bfc2 = (const float*)d_in[16];
    p.out = (float*)d_out;

    p.xb     = (u16*)(W + 0);             // 50000*96 bf16
    p.h1     = (u16*)(W + 9600000);       // 50000*128 bf16 each
    p.h2     = (u16*)(W + 22400000);
    p.h3     = (u16*)(W + 35200000);
    p.zlp    = (u16*)(W + 48000000);
    p.zq     = (u16*)(W + 60800000);
    p.WT0    = (u16*)(W + 73600000);
    p.WT1    = (u16*)(W + 73649152);
    p.WT2    = (u16*)(W + 73714688);
    p.iQl0   = (float*)(W + 73780224);
    p.iQr0   = (float*)(W + 74036224);
    p.iQl1   = (float*)(W + 74292224);
    p.iQr1   = (float*)(W + 74548224);
    p.iQl2   = (float*)(W + 74804224);
    p.iQr2   = (float*)(W + 75060224);
    p.start  = (int*)(W + 75316224);      // NG+1
    p.cnt    = (int*)(W + 75318272);      // NN
    p.csr    = (u16*)(W + 75518336);      // NN*128 u16 = 12.8 MB
    p.ebin   = (u32*)(W + 88318336);      // 256*8192 u32 = 8 MB
    p.grescnt= (int*)(W + 96706560);      // 256 x16 padded ints (16 KB)

    hipMemsetAsync(p.grescnt, 0, 256 * 16 * sizeof(int), stream);
    k_prep<<<PREP_GRID, 256, 0, stream>>>(p);

    // layer 0: binB || mfma<96> packed (independent after prep)
    k_l0<<<NRANGE + GGEMM, 256, 0, stream>>>(p);
    k_g<<<GGATH, 256, 0, stream>>>(p, p.h1);

    // layer 1
    k_mfma128<<<GGEMM, 256, 0, stream>>>(p, p.h1, p.WT1, p.iQl1, p.iQr1);
    k_g<<<GGATH, 256, 0, stream>>>(p, p.h2);

    // layer 2
    k_mfma128<<<GGEMM, 256, 0, stream>>>(p, p.h2, p.WT2, p.iQl2, p.iQr2);
    k_g<<<GGATH, 256, 0, stream>>>(p, p.h3);

    // pool + head
    k_poolfc<<<NG, 384, 0, stream>>>(p);
}